// Round 11
// baseline (787.952 us; speedup 1.0000x reference)
//
#include <hip/hip_runtime.h>
#include <math.h>

#define NPTS 262144
#define KCL  256
#define DDIM 64
#define ALPHA_DP 1.0f

#define ROWS_PER_TILE 16
#define WAVES_PER_BLK 8
#define TILES_PER_WAVE 2
#define TILES_PER_BLK  (WAVES_PER_BLK * TILES_PER_WAVE)   // 16
#define NTILE          (NPTS / ROWS_PER_TILE)             // 16384
#define NBLK_MAIN      (NTILE / TILES_PER_BLK)            // 1024
#define NPART          NTILE

// ws float offsets
#define OFF_ELOGPI 32768
#define OFF_BASE   33024
#define OFF_KLB    33280
#define OFF_KLP    33281
#define OFF_PART   33537

#define LN2_F    0.6931471805599453f
#define LOG2PI_F 1.8378770664093453f

typedef _Float16 f16x8 __attribute__((ext_vector_type(8)));
typedef float    f32x4 __attribute__((ext_vector_type(4)));

__device__ __forceinline__ float digamma_f(float x) {
  float r = 0.0f;
  while (x < 6.0f) { r -= 1.0f / x; x += 1.0f; }
  float inv  = 1.0f / x;
  float inv2 = inv * inv;
  return r + logf(x) - 0.5f * inv
       - inv2 * (0.083333333333333333f
         - inv2 * (0.008333333333333333f
           - inv2 * 0.003968253968253968f));
}

// --- P1: stick-breaking terms + cumsum + KL(Beta) --------------------------
__global__ void dpmm_beta(const float* __restrict__ u, const float* __restrict__ v,
                          float* __restrict__ ws) {
  __shared__ float eb_s[KCL], e1b_s[KCL], klb_s[KCL];
  const int k = threadIdx.x;
  float uk = u[k], vk = v[k];
  float ds  = digamma_f(uk + vk);
  float eb  = digamma_f(uk) - ds;
  float e1b = digamma_f(vk) - ds;
  eb_s[k] = eb; e1b_s[k] = e1b;
  klb_s[k] = lgammaf(uk + vk) - lgammaf(uk) - lgammaf(vk)
           - (lgammaf(1.0f + ALPHA_DP) - lgammaf(ALPHA_DP))
           + (uk - 1.0f) * eb + (vk - ALPHA_DP) * e1b;
  __syncthreads();
  if (k == 0) {
    float run = 0.0f;
    for (int j = 0; j < KCL; ++j) { ws[OFF_ELOGPI + j] = eb_s[j] + run; run += e1b_s[j]; }
    double t = 0.0;
    for (int j = 0; j < KCL; ++j) t += (double)klb_s[j];
    ws[OFF_KLB] = (float)t;
  }
}

// --- P2: per-(k,d) W split + per-k base & KL parts (one wave per cluster) --
// Wp layout (fp16): idx = ((s*16 + T)*64 + lane)*8 + e
//   s=0..3: Wh, s=4..7: Wl for k-row ks*32 + g*8 + e; lane = g*16 + c15
//   cluster k at tile T=(k&15), lane-col c15=(k>>4)
__global__ __launch_bounds__(64) void dpmm_w(
    const float* __restrict__ tau, const float* __restrict__ c,
    const float* __restrict__ n,   const float* __restrict__ B,
    const float* __restrict__ tau0, const float* __restrict__ c0,
    const float* __restrict__ n0,  const float* __restrict__ B0,
    float* __restrict__ ws) {
  const int k = blockIdx.x, d = threadIdx.x;
  _Float16* Wp = (_Float16*)ws;

  float nk = n[k], ck = c[k], n0k = n0[k], c0k = c0[k];
  float Bkd = B[k * DDIM + d],   tkd  = tau[k * DDIM + d];
  float B0kd = B0[k * DDIM + d], t0kd = tau0[k * DDIM + d];
  float Elam = nk / Bkd;
  float wb = Elam * tkd;        // coeff of x   (k-row d)
  float wa = -0.5f * Elam;      // coeff of x^2 (k-row 64+d)

  const int T = k & 15, c15k = k >> 4;
  {
    int kk = d;
    int ks = kk >> 5, g = (kk >> 3) & 3, e = kk & 7;
    int lanei = g * 16 + c15k;
    _Float16 h = (_Float16)wb, lo = (_Float16)(wb - (float)h);
    Wp[(( ks      * 16 + T) * 64 + lanei) * 8 + e] = h;
    Wp[(((4 + ks) * 16 + T) * 64 + lanei) * 8 + e] = lo;
  }
  {
    int kk = 64 + d;
    int ks = kk >> 5, g = (kk >> 3) & 3, e = kk & 7;
    int lanei = g * 16 + c15k;
    _Float16 h = (_Float16)wa, lo = (_Float16)(wa - (float)h);
    Wp[(( ks      * 16 + T) * 64 + lanei) * 8 + e] = h;
    Wp[(((4 + ks) * 16 + T) * 64 + lanei) * 8 + e] = lo;
  }

  float a = 0.5f * nk, a0 = 0.5f * n0k;
  float dga = digamma_f(a);
  float lga = lgammaf(a), lga0 = lgammaf(a0);
  float b = 0.5f * Bkd, b0 = 0.5f * B0kd;
  float klg = (a - a0) * dga - lga + lga0
            + a0 * (logf(b) - logf(b0)) + a * (b0 - b) / b;
  float dt = tkd - t0kd;
  float knq = Elam * dt * dt;
  float negLogB = -logf(Bkd);
  float et2 = Elam * tkd * tkd;

  #pragma unroll
  for (int off = 32; off; off >>= 1) {
    klg      += __shfl_xor(klg, off, 64);
    knq      += __shfl_xor(knq, off, 64);
    negLogB  += __shfl_xor(negLogB, off, 64);
    et2      += __shfl_xor(et2, off, 64);
  }
  if (d == 0) {
    float sumEloglam = (float)DDIM * (dga + LN2_F) + negLogB;
    ws[OFF_BASE + k] = ws[OFF_ELOGPI + k]
        + 0.5f * (sumEloglam - (float)DDIM * LOG2PI_F
                  - (float)DDIM / ck - et2);
    float kln = 0.5f * (float)DDIM * (c0k / ck - 1.0f + logf(ck / c0k))
              + 0.5f * c0k * knq;
    ws[OFF_KLP + k] = klg + kln;
  }
}

__device__ __forceinline__ void split8(const float* v, f16x8& h, f16x8& l) {
  #pragma unroll
  for (int e = 0; e < 8; ++e) {
    _Float16 hh = (_Float16)v[e];
    h[e] = hh;
    l[e] = (_Float16)(v[e] - (float)hh);
  }
}

extern __shared__ _Float16 W_sh[];   // 128 KB

// Stage W once per block (single barrier), then each wave free-runs over
// TILES_PER_WAVE independent 16-row tiles: ds_read_b128 B-frags (conflict-
// free), no further syncs -> waves pipeline across LDS/MFMA/VALU/store.
__global__ __launch_bounds__(512) void dpmm_mfma(
    const float* __restrict__ x, const _Float16* __restrict__ Wp,
    const float* __restrict__ base,
    float* __restrict__ pi, float* __restrict__ partial) {
  const int tid  = threadIdx.x;
  const int lane = tid & 63;
  const int w    = tid >> 6;
  const int g    = lane >> 4;
  const int c15  = lane & 15;

  // ---- stage full W panel once ----
  {
    const float4* gsrc = (const float4*)Wp;     // 8192 float4
    float4* ldst = (float4*)W_sh;
    #pragma unroll
    for (int it = 0; it < 16; ++it) {
      int idx = it * 512 + tid;
      ldst[idx] = gsrc[idx];
    }
  }
  __syncthreads();                              // the only barrier

  #pragma unroll 1
  for (int t = 0; t < TILES_PER_WAVE; ++t) {
    const long tile = (long)blockIdx.x * TILES_PER_BLK + t * WAVES_PER_BLK + w;
    const long row0 = tile * ROWS_PER_TILE;

    // x loads (NT: read-once stream)
    const float* xr = x + (row0 + c15) * DDIM + g * 8;
    f32x4 x0 = __builtin_nontemporal_load((const f32x4*)(xr + 0));
    f32x4 x1 = __builtin_nontemporal_load((const f32x4*)(xr + 4));
    f32x4 x2 = __builtin_nontemporal_load((const f32x4*)(xr + 32));
    f32x4 x3 = __builtin_nontemporal_load((const f32x4*)(xr + 36));

    f16x8 ah[4], al[4];
    {
      float c0[8] = {x0.x,x0.y,x0.z,x0.w,x1.x,x1.y,x1.z,x1.w};
      float c1[8] = {x2.x,x2.y,x2.z,x2.w,x3.x,x3.y,x3.z,x3.w};
      float q0[8], q1[8];
      #pragma unroll
      for (int e = 0; e < 8; ++e) { q0[e] = c0[e]*c0[e]; q1[e] = c1[e]*c1[e]; }
      split8(c0, ah[0], al[0]);   // k 0..31   : x
      split8(c1, ah[1], al[1]);   // k 32..63  : x
      split8(q0, ah[2], al[2]);   // k 64..95  : x^2
      split8(q1, ah[3], al[3]);   // k 96..127 : x^2
    }

    f32x4 acc[16];
    #pragma unroll
    for (int T = 0; T < 16; ++T) {
      float bb = base[c15 * 16 + T];
      f32x4 bv = { bb, bb, bb, bb };
      acc[T] = bv;
    }

    // GEMM from LDS: Wh (s=0..3) feeds ah+al, Wl (s=4..7) feeds ah
    #pragma unroll
    for (int s = 0; s < 4; ++s) {
      #pragma unroll
      for (int T = 0; T < 16; ++T) {
        f16x8 b = *(const f16x8*)&W_sh[(size_t)((s * 16 + T) * 64 + lane) * 8];
        acc[T] = __builtin_amdgcn_mfma_f32_16x16x32_f16(ah[s], b, acc[T], 0, 0, 0);
        acc[T] = __builtin_amdgcn_mfma_f32_16x16x32_f16(al[s], b, acc[T], 0, 0, 0);
      }
    }
    #pragma unroll
    for (int s = 4; s < 8; ++s) {
      #pragma unroll
      for (int T = 0; T < 16; ++T) {
        f16x8 b = *(const f16x8*)&W_sh[(size_t)((s * 16 + T) * 64 + lane) * 8];
        acc[T] = __builtin_amdgcn_mfma_f32_16x16x32_f16(ah[s - 4], b, acc[T], 0, 0, 0);
      }
    }

    // softmax epilogue; row = g*4+j, lane c15 owns cols c15*16..+15
    float wls = 0.0f;
    #pragma unroll
    for (int j = 0; j < 4; ++j) {
      float m = acc[0][j];
      #pragma unroll
      for (int T = 1; T < 16; ++T) m = fmaxf(m, acc[T][j]);
      m = fmaxf(m, __shfl_xor(m, 1, 64));
      m = fmaxf(m, __shfl_xor(m, 2, 64));
      m = fmaxf(m, __shfl_xor(m, 4, 64));
      m = fmaxf(m, __shfl_xor(m, 8, 64));
      float ev[16]; float s = 0.0f;
      #pragma unroll
      for (int T = 0; T < 16; ++T) { ev[T] = __expf(acc[T][j] - m); s += ev[T]; }
      s += __shfl_xor(s, 1, 64);
      s += __shfl_xor(s, 2, 64);
      s += __shfl_xor(s, 4, 64);
      s += __shfl_xor(s, 8, 64);
      float rs = 1.0f / s;
      float* pr = pi + (size_t)(row0 + g * 4 + j) * KCL + c15 * 16;
      #pragma unroll
      for (int ch = 0; ch < 4; ++ch) {
        f32x4 pv = { ev[4*ch+0] * rs, ev[4*ch+1] * rs,
                     ev[4*ch+2] * rs, ev[4*ch+3] * rs };
        *(f32x4*)(pr + 4 * ch) = pv;
      }
      wls += m + __logf(s);       // uniform across each 16-lane group
    }
    wls += __shfl_xor(wls, 16, 64);
    wls += __shfl_xor(wls, 32, 64);
    if (lane == 0) partial[tile] = wls;
  }
}

__global__ void dpmm_fin(const float* __restrict__ ws,
                         float* __restrict__ out_elbo) {
  __shared__ double red[256];
  const int t = threadIdx.x;
  double s = 0.0;
  for (int i = t; i < NPART; i += 256) s += (double)ws[OFF_PART + i];
  s -= (double)ws[OFF_KLP + t];
  red[t] = s;
  __syncthreads();
  for (int off = 128; off; off >>= 1) {
    if (t < off) red[t] += red[t + off];
    __syncthreads();
  }
  if (t == 0) out_elbo[0] = (float)(red[0] - (double)ws[OFF_KLB]);
}

extern "C" void kernel_launch(void* const* d_in, const int* in_sizes, int n_in,
                              void* d_out, int out_size, void* d_ws, size_t ws_size,
                              hipStream_t stream) {
  const float* x    = (const float*)d_in[0];
  const float* u    = (const float*)d_in[1];
  const float* v    = (const float*)d_in[2];
  const float* tau  = (const float*)d_in[3];
  const float* c    = (const float*)d_in[4];
  const float* n    = (const float*)d_in[5];
  const float* B    = (const float*)d_in[6];
  const float* tau0 = (const float*)d_in[7];
  const float* c0   = (const float*)d_in[8];
  const float* n0   = (const float*)d_in[9];
  const float* B0   = (const float*)d_in[10];

  float* out = (float*)d_out;
  float* ws  = (float*)d_ws;

  (void)hipFuncSetAttribute((const void*)dpmm_mfma,
                            hipFuncAttributeMaxDynamicSharedMemorySize, 131072);

  dpmm_beta<<<1, KCL, 0, stream>>>(u, v, ws);
  dpmm_w<<<KCL, DDIM, 0, stream>>>(tau, c, n, B, tau0, c0, n0, B0, ws);

  const _Float16* Wp = (const _Float16*)ws;
  const float* base  = ws + OFF_BASE;
  float* partial     = ws + OFF_PART;

  dpmm_mfma<<<NBLK_MAIN, 512, 131072, stream>>>(x, Wp, base, out, partial);
  dpmm_fin<<<1, 256, 0, stream>>>(ws, out + (size_t)NPTS * KCL);
}

// Round 12
// 162.109 us; speedup vs baseline: 4.8606x; 4.8606x over previous
//
#include <hip/hip_runtime.h>
#include <math.h>

#define NPTS 262144
#define KCL  256
#define DDIM 64
#define ALPHA_DP 1.0f

#define ROWS_PER_WAVE 16
#define WAVES_PER_BLK 4
#define ROWS_PER_BLK  (ROWS_PER_WAVE * WAVES_PER_BLK)   // 64
#define NBLK_MAIN     (NPTS / ROWS_PER_BLK)             // 4096
#define NPART         (NPTS / ROWS_PER_WAVE)            // 16384

// ws float offsets
#define OFF_ELOGPI 32768
#define OFF_BASE   33024
#define OFF_KLB    33280
#define OFF_KLP    33281
#define OFF_PART   33537

#define LN2_F    0.6931471805599453f
#define LOG2PI_F 1.8378770664093453f

typedef _Float16 f16x8 __attribute__((ext_vector_type(8)));
typedef float    f32x4 __attribute__((ext_vector_type(4)));

__device__ __forceinline__ float digamma_f(float x) {
  float r = 0.0f;
  while (x < 6.0f) { r -= 1.0f / x; x += 1.0f; }
  float inv  = 1.0f / x;
  float inv2 = inv * inv;
  return r + logf(x) - 0.5f * inv
       - inv2 * (0.083333333333333333f
         - inv2 * (0.008333333333333333f
           - inv2 * 0.003968253968253968f));
}

// --- P1: stick-breaking terms + cumsum + KL(Beta) --------------------------
__global__ void dpmm_beta(const float* __restrict__ u, const float* __restrict__ v,
                          float* __restrict__ ws) {
  __shared__ float eb_s[KCL], e1b_s[KCL], klb_s[KCL];
  const int k = threadIdx.x;
  float uk = u[k], vk = v[k];
  float ds  = digamma_f(uk + vk);
  float eb  = digamma_f(uk) - ds;
  float e1b = digamma_f(vk) - ds;
  eb_s[k] = eb; e1b_s[k] = e1b;
  klb_s[k] = lgammaf(uk + vk) - lgammaf(uk) - lgammaf(vk)
           - (lgammaf(1.0f + ALPHA_DP) - lgammaf(ALPHA_DP))
           + (uk - 1.0f) * eb + (vk - ALPHA_DP) * e1b;
  __syncthreads();
  if (k == 0) {
    float run = 0.0f;
    for (int j = 0; j < KCL; ++j) { ws[OFF_ELOGPI + j] = eb_s[j] + run; run += e1b_s[j]; }
    double t = 0.0;
    for (int j = 0; j < KCL; ++j) t += (double)klb_s[j];
    ws[OFF_KLB] = (float)t;
  }
}

// --- P2: per-(k,d) W split + per-k base & KL parts (one wave per cluster) --
// Wp layout (fp16): idx = ((s*16 + T)*64 + lane)*8 + e
//   s=0..3: Wh, s=4..7: Wl for k-row ks*32 + g*8 + e; lane = g*16 + c15
//   cluster k at tile T=(k&15), lane-col c15=(k>>4)
__global__ __launch_bounds__(64) void dpmm_w(
    const float* __restrict__ tau, const float* __restrict__ c,
    const float* __restrict__ n,   const float* __restrict__ B,
    const float* __restrict__ tau0, const float* __restrict__ c0,
    const float* __restrict__ n0,  const float* __restrict__ B0,
    float* __restrict__ ws) {
  const int k = blockIdx.x, d = threadIdx.x;
  _Float16* Wp = (_Float16*)ws;

  float nk = n[k], ck = c[k], n0k = n0[k], c0k = c0[k];
  float Bkd = B[k * DDIM + d],   tkd  = tau[k * DDIM + d];
  float B0kd = B0[k * DDIM + d], t0kd = tau0[k * DDIM + d];
  float Elam = nk / Bkd;
  float wb = Elam * tkd;        // coeff of x   (k-row d)
  float wa = -0.5f * Elam;      // coeff of x^2 (k-row 64+d)

  const int T = k & 15, c15k = k >> 4;
  {
    int kk = d;
    int ks = kk >> 5, g = (kk >> 3) & 3, e = kk & 7;
    int lanei = g * 16 + c15k;
    _Float16 h = (_Float16)wb, lo = (_Float16)(wb - (float)h);
    Wp[(( ks      * 16 + T) * 64 + lanei) * 8 + e] = h;
    Wp[(((4 + ks) * 16 + T) * 64 + lanei) * 8 + e] = lo;
  }
  {
    int kk = 64 + d;
    int ks = kk >> 5, g = (kk >> 3) & 3, e = kk & 7;
    int lanei = g * 16 + c15k;
    _Float16 h = (_Float16)wa, lo = (_Float16)(wa - (float)h);
    Wp[(( ks      * 16 + T) * 64 + lanei) * 8 + e] = h;
    Wp[(((4 + ks) * 16 + T) * 64 + lanei) * 8 + e] = lo;
  }

  float a = 0.5f * nk, a0 = 0.5f * n0k;
  float dga = digamma_f(a);
  float lga = lgammaf(a), lga0 = lgammaf(a0);
  float b = 0.5f * Bkd, b0 = 0.5f * B0kd;
  float klg = (a - a0) * dga - lga + lga0
            + a0 * (logf(b) - logf(b0)) + a * (b0 - b) / b;
  float dt = tkd - t0kd;
  float knq = Elam * dt * dt;
  float negLogB = -logf(Bkd);
  float et2 = Elam * tkd * tkd;

  #pragma unroll
  for (int off = 32; off; off >>= 1) {
    klg      += __shfl_xor(klg, off, 64);
    knq      += __shfl_xor(knq, off, 64);
    negLogB  += __shfl_xor(negLogB, off, 64);
    et2      += __shfl_xor(et2, off, 64);
  }
  if (d == 0) {
    float sumEloglam = (float)DDIM * (dga + LN2_F) + negLogB;
    ws[OFF_BASE + k] = ws[OFF_ELOGPI + k]
        + 0.5f * (sumEloglam - (float)DDIM * LOG2PI_F
                  - (float)DDIM / ck - et2);
    float kln = 0.5f * (float)DDIM * (c0k / ck - 1.0f + logf(ck / c0k))
              + 0.5f * c0k * knq;
    ws[OFF_KLP + k] = klg + kln;
  }
}

__device__ __forceinline__ void split8(const float* v, f16x8& h, f16x8& l) {
  #pragma unroll
  for (int e = 0; e < 8; ++e) {
    _Float16 hh = (_Float16)v[e];
    h[e] = hh;
    l[e] = (_Float16)(v[e] - (float)hh);
  }
}

// R9 structure + T14 async staging: 8x 16KB chunks double-buffered in 32KB
// LDS. Loads for chunk c+1 are issued one full GEMM-chunk before their
// ds_write -> L2 latency hides under MFMA. One barrier per chunk (write
// targets the buffer whose readers finished before the previous barrier).
// NOT (256,4): 128-VGPR cap spilled in R3/R11; (256,3) caps ~170 unified.
__global__ __launch_bounds__(256, 3) void dpmm_mfma(
    const float* __restrict__ x, const _Float16* __restrict__ Wp,
    const float* __restrict__ base,
    float* __restrict__ pi, float* __restrict__ partial) {
  __shared__ _Float16 W_sh[2][8192];            // 2 x 16KB chunk buffers
  const int tid  = threadIdx.x;
  const int lane = tid & 63;
  const int w    = tid >> 6;
  const int g    = lane >> 4;
  const int c15  = lane & 15;

  // ---- x loads first ----
  const long row0 = (long)blockIdx.x * ROWS_PER_BLK + (long)w * ROWS_PER_WAVE;
  const float* xr = x + (row0 + c15) * DDIM + g * 8;
  float4 x0 = *(const float4*)(xr + 0);
  float4 x1 = *(const float4*)(xr + 4);
  float4 x2 = *(const float4*)(xr + 32);
  float4 x3 = *(const float4*)(xr + 36);

  // ---- prologue staging: chunk0 -> buf0, issue chunk1 loads ----
  const f32x4* Wv = (const f32x4*)Wp;           // chunk c = [c*1024, +1024)
  f32x4 st[4];
  #pragma unroll
  for (int i = 0; i < 4; ++i) st[i] = Wv[i * 256 + tid];

  // ---- build A fragments while chunk0 is in flight ----
  f16x8 ah[4], al[4];
  {
    float c0[8] = {x0.x,x0.y,x0.z,x0.w,x1.x,x1.y,x1.z,x1.w};
    float c1[8] = {x2.x,x2.y,x2.z,x2.w,x3.x,x3.y,x3.z,x3.w};
    float q0[8], q1[8];
    #pragma unroll
    for (int e = 0; e < 8; ++e) { q0[e] = c0[e]*c0[e]; q1[e] = c1[e]*c1[e]; }
    split8(c0, ah[0], al[0]);   // k 0..31   : x
    split8(c1, ah[1], al[1]);   // k 32..63  : x
    split8(q0, ah[2], al[2]);   // k 64..95  : x^2
    split8(q1, ah[3], al[3]);   // k 96..127 : x^2
  }

  // acc init: lane c15, tile T -> cluster c15*16+T
  f32x4 acc[16];
  #pragma unroll
  for (int T = 0; T < 16; ++T) {
    float bb = base[c15 * 16 + T];
    f32x4 bv = { bb, bb, bb, bb };
    acc[T] = bv;
  }

  {
    f32x4* dst = (f32x4*)W_sh[0];
    #pragma unroll
    for (int i = 0; i < 4; ++i) dst[i * 256 + tid] = st[i];  // waits chunk0
    #pragma unroll
    for (int i = 0; i < 4; ++i) st[i] = Wv[1024 + i * 256 + tid];  // chunk1
  }
  __syncthreads();

  // ---- chunk loop: GEMM(c) || chunk c+1 arriving; write c+1; load c+2 ----
  #pragma unroll
  for (int c = 0; c < 8; ++c) {
    const _Float16* Ws = W_sh[c & 1];
    if (c < 4) {                       // Wh slice c: feeds ah and al
      #pragma unroll
      for (int T = 0; T < 16; ++T) {
        f16x8 b = *(const f16x8*)&Ws[(T * 64 + lane) * 8];
        acc[T] = __builtin_amdgcn_mfma_f32_16x16x32_f16(ah[c], b, acc[T], 0, 0, 0);
        acc[T] = __builtin_amdgcn_mfma_f32_16x16x32_f16(al[c], b, acc[T], 0, 0, 0);
      }
    } else {                           // Wl slice c-4: feeds ah only
      #pragma unroll
      for (int T = 0; T < 16; ++T) {
        f16x8 b = *(const f16x8*)&Ws[(T * 64 + lane) * 8];
        acc[T] = __builtin_amdgcn_mfma_f32_16x16x32_f16(ah[c - 4], b, acc[T], 0, 0, 0);
      }
    }
    if (c < 7) {
      f32x4* dst = (f32x4*)W_sh[(c + 1) & 1];
      #pragma unroll
      for (int i = 0; i < 4; ++i) dst[i * 256 + tid] = st[i];
      if (c < 6) {
        #pragma unroll
        for (int i = 0; i < 4; ++i)
          st[i] = Wv[(size_t)(c + 2) * 1024 + i * 256 + tid];
      }
      __syncthreads();
    }
  }

  // ---- softmax epilogue; row = g*4+j, lane c15 owns cols c15*16..+15 ----
  float wls = 0.0f;
  #pragma unroll
  for (int j = 0; j < 4; ++j) {
    float m = acc[0][j];
    #pragma unroll
    for (int T = 1; T < 16; ++T) m = fmaxf(m, acc[T][j]);
    m = fmaxf(m, __shfl_xor(m, 1, 64));
    m = fmaxf(m, __shfl_xor(m, 2, 64));
    m = fmaxf(m, __shfl_xor(m, 4, 64));
    m = fmaxf(m, __shfl_xor(m, 8, 64));
    float ev[16]; float s = 0.0f;
    #pragma unroll
    for (int T = 0; T < 16; ++T) { ev[T] = __expf(acc[T][j] - m); s += ev[T]; }
    s += __shfl_xor(s, 1, 64);
    s += __shfl_xor(s, 2, 64);
    s += __shfl_xor(s, 4, 64);
    s += __shfl_xor(s, 8, 64);
    float rs = 1.0f / s;
    float* pr = pi + (size_t)(row0 + g * 4 + j) * KCL + c15 * 16;
    #pragma unroll
    for (int ch = 0; ch < 4; ++ch) {
      f32x4 pv = { ev[4*ch+0] * rs, ev[4*ch+1] * rs,
                   ev[4*ch+2] * rs, ev[4*ch+3] * rs };
      *(f32x4*)(pr + 4 * ch) = pv;
    }
    wls += m + __logf(s);       // uniform across each 16-lane group
  }
  wls += __shfl_xor(wls, 16, 64);
  wls += __shfl_xor(wls, 32, 64);
  if (lane == 0) partial[blockIdx.x * WAVES_PER_BLK + w] = wls;
}

__global__ void dpmm_fin(const float* __restrict__ ws,
                         float* __restrict__ out_elbo) {
  __shared__ double red[256];
  const int t = threadIdx.x;
  double s = 0.0;
  for (int i = t; i < NPART; i += 256) s += (double)ws[OFF_PART + i];
  s -= (double)ws[OFF_KLP + t];
  red[t] = s;
  __syncthreads();
  for (int off = 128; off; off >>= 1) {
    if (t < off) red[t] += red[t + off];
    __syncthreads();
  }
  if (t == 0) out_elbo[0] = (float)(red[0] - (double)ws[OFF_KLB]);
}

extern "C" void kernel_launch(void* const* d_in, const int* in_sizes, int n_in,
                              void* d_out, int out_size, void* d_ws, size_t ws_size,
                              hipStream_t stream) {
  const float* x    = (const float*)d_in[0];
  const float* u    = (const float*)d_in[1];
  const float* v    = (const float*)d_in[2];
  const float* tau  = (const float*)d_in[3];
  const float* c    = (const float*)d_in[4];
  const float* n    = (const float*)d_in[5];
  const float* B    = (const float*)d_in[6];
  const float* tau0 = (const float*)d_in[7];
  const float* c0   = (const float*)d_in[8];
  const float* n0   = (const float*)d_in[9];
  const float* B0   = (const float*)d_in[10];

  float* out = (float*)d_out;
  float* ws  = (float*)d_ws;

  dpmm_beta<<<1, KCL, 0, stream>>>(u, v, ws);
  dpmm_w<<<KCL, DDIM, 0, stream>>>(tau, c, n, B, tau0, c0, n0, B0, ws);

  const _Float16* Wp = (const _Float16*)ws;
  const float* base  = ws + OFF_BASE;
  float* partial     = ws + OFF_PART;

  dpmm_mfma<<<NBLK_MAIN, 256, 0, stream>>>(x, Wp, base, out, partial);
  dpmm_fin<<<1, 256, 0, stream>>>(ws, out + (size_t)NPTS * KCL);
}

// Round 13
// 120.489 us; speedup vs baseline: 6.5396x; 1.3454x over previous
//
#include <hip/hip_runtime.h>
#include <math.h>

#define NPTS 262144
#define KCL  256
#define DDIM 64
#define ALPHA_DP 1.0f

#define ROWS_PER_WAVE 32
#define WAVES_PER_BLK 4
#define ROWS_PER_BLK  (ROWS_PER_WAVE * WAVES_PER_BLK)   // 128
#define NBLK_MAIN     (NPTS / ROWS_PER_BLK)             // 2048
#define NPART         (NPTS / ROWS_PER_WAVE)            // 8192

// ws float offsets
#define OFF_ELOGPI 32768
#define OFF_BASE   33024
#define OFF_KLB    33280
#define OFF_KLP    33281
#define OFF_PART   33537

#define LN2_F    0.6931471805599453f
#define LOG2PI_F 1.8378770664093453f

typedef _Float16 f16x8  __attribute__((ext_vector_type(8)));
typedef float    f32x4  __attribute__((ext_vector_type(4)));
typedef float    f32x16 __attribute__((ext_vector_type(16)));

__device__ __forceinline__ float digamma_f(float x) {
  float r = 0.0f;
  while (x < 6.0f) { r -= 1.0f / x; x += 1.0f; }
  float inv  = 1.0f / x;
  float inv2 = inv * inv;
  return r + logf(x) - 0.5f * inv
       - inv2 * (0.083333333333333333f
         - inv2 * (0.008333333333333333f
           - inv2 * 0.003968253968253968f));
}

// --- P1: stick-breaking terms + cumsum + KL(Beta) --------------------------
__global__ void dpmm_beta(const float* __restrict__ u, const float* __restrict__ v,
                          float* __restrict__ ws) {
  __shared__ float eb_s[KCL], e1b_s[KCL], klb_s[KCL];
  const int k = threadIdx.x;
  float uk = u[k], vk = v[k];
  float ds  = digamma_f(uk + vk);
  float eb  = digamma_f(uk) - ds;
  float e1b = digamma_f(vk) - ds;
  eb_s[k] = eb; e1b_s[k] = e1b;
  klb_s[k] = lgammaf(uk + vk) - lgammaf(uk) - lgammaf(vk)
           - (lgammaf(1.0f + ALPHA_DP) - lgammaf(ALPHA_DP))
           + (uk - 1.0f) * eb + (vk - ALPHA_DP) * e1b;
  __syncthreads();
  if (k == 0) {
    float run = 0.0f;
    for (int j = 0; j < KCL; ++j) { ws[OFF_ELOGPI + j] = eb_s[j] + run; run += e1b_s[j]; }
    double t = 0.0;
    for (int j = 0; j < KCL; ++j) t += (double)klb_s[j];
    ws[OFF_KLB] = (float)t;
  }
}

// --- P2: W split into 32x32x16 B-fragments + per-k base & KL parts ---------
// Frag layout: frag fi (0..63 Wh, 64..127 Wl), fi%64 = s*8 + ct, s=krow>>4.
//   element: Wp[fi*512 + lane*8 + e];  b-frag: col=lane&31, k=(lane>>5)*8+e
// Cluster k at tile ct=k&7, col=k>>3  -> lane owns 8 contiguous clusters.
__global__ __launch_bounds__(64) void dpmm_w(
    const float* __restrict__ tau, const float* __restrict__ c,
    const float* __restrict__ n,   const float* __restrict__ B,
    const float* __restrict__ tau0, const float* __restrict__ c0,
    const float* __restrict__ n0,  const float* __restrict__ B0,
    float* __restrict__ ws) {
  const int k = blockIdx.x, d = threadIdx.x;
  _Float16* Wp = (_Float16*)ws;

  float nk = n[k], ck = c[k], n0k = n0[k], c0k = c0[k];
  float Bkd = B[k * DDIM + d],   tkd  = tau[k * DDIM + d];
  float B0kd = B0[k * DDIM + d], t0kd = tau0[k * DDIM + d];
  float Elam = nk / Bkd;
  float wb = Elam * tkd;        // coeff of x   (krow d)
  float wa = -0.5f * Elam;      // coeff of x^2 (krow 64+d)

  const int ct = k & 7, col = k >> 3;
  int   kks[2] = { d, 64 + d };
  float wvs[2] = { wb, wa };
  #pragma unroll
  for (int q = 0; q < 2; ++q) {
    int kk = kks[q]; float wq = wvs[q];
    int s = kk >> 4, rem = kk & 15, h = rem >> 3, e = rem & 7;
    int lanei = col + h * 32;
    _Float16 hi = (_Float16)wq, lo = (_Float16)(wq - (float)hi);
    Wp[(( s * 8 + ct)      ) * 512 + lanei * 8 + e] = hi;
    Wp[((64 + s * 8 + ct)  ) * 512 + lanei * 8 + e] = lo;
  }

  float a = 0.5f * nk, a0 = 0.5f * n0k;
  float dga = digamma_f(a);
  float lga = lgammaf(a), lga0 = lgammaf(a0);
  float b = 0.5f * Bkd, b0 = 0.5f * B0kd;
  float klg = (a - a0) * dga - lga + lga0
            + a0 * (logf(b) - logf(b0)) + a * (b0 - b) / b;
  float dt = tkd - t0kd;
  float knq = Elam * dt * dt;
  float negLogB = -logf(Bkd);
  float et2 = Elam * tkd * tkd;

  #pragma unroll
  for (int off = 32; off; off >>= 1) {
    klg      += __shfl_xor(klg, off, 64);
    knq      += __shfl_xor(knq, off, 64);
    negLogB  += __shfl_xor(negLogB, off, 64);
    et2      += __shfl_xor(et2, off, 64);
  }
  if (d == 0) {
    float sumEloglam = (float)DDIM * (dga + LN2_F) + negLogB;
    ws[OFF_BASE + k] = ws[OFF_ELOGPI + k]
        + 0.5f * (sumEloglam - (float)DDIM * LOG2PI_F
                  - (float)DDIM / ck - et2);
    float kln = 0.5f * (float)DDIM * (c0k / ck - 1.0f + logf(ck / c0k))
              + 0.5f * c0k * knq;
    ws[OFF_KLP + k] = klg + kln;
  }
}

__device__ __forceinline__ void split8(const float* v, f16x8& h, f16x8& l) {
  #pragma unroll
  for (int e = 0; e < 8; ++e) {
    _Float16 hh = (_Float16)v[e];
    h[e] = hh;
    l[e] = (_Float16)(v[e] - (float)hh);
  }
}

// 32x32x16 MFMA, 32 rows/wave, chunked double-buffer staging (R12 schedule).
// (256,2): acc 128 + frags 64 + staging fits 2 waves/SIMD; NOT (256,4) (spill).
__global__ __launch_bounds__(256, 2) void dpmm_mfma(
    const float* __restrict__ x, const _Float16* __restrict__ Wp,
    const float* __restrict__ base,
    float* __restrict__ pi, float* __restrict__ partial) {
  __shared__ _Float16 W_sh[2][8192];            // 2 x 16KB chunk buffers
  const int tid  = threadIdx.x;
  const int lane = tid & 63;
  const int w    = tid >> 6;
  const int col  = lane & 31;                   // tile col / A row
  const int h    = lane >> 5;                   // k-half

  // ---- x loads first: lane's row, features h*8+{0..7} per 16-slice ----
  const long row0 = (long)blockIdx.x * ROWS_PER_BLK + (long)w * ROWS_PER_WAVE;
  const float* xr = x + (row0 + col) * DDIM + h * 8;
  float4 xa[4], xb[4];
  #pragma unroll
  for (int s = 0; s < 4; ++s) {
    xa[s] = *(const float4*)(xr + s * 16);
    xb[s] = *(const float4*)(xr + s * 16 + 4);
  }

  // ---- prologue staging: chunk0 loads ----
  const f32x4* Wv = (const f32x4*)Wp;           // chunk c = [c*1024, +1024)
  f32x4 st[4];
  #pragma unroll
  for (int i = 0; i < 4; ++i) st[i] = Wv[i * 256 + tid];

  // ---- A fragments: s=0..3 x, s=4..7 x^2 (hi/lo) ----
  f16x8 ah[8], al[8];
  #pragma unroll
  for (int s = 0; s < 4; ++s) {
    float cv[8] = {xa[s].x,xa[s].y,xa[s].z,xa[s].w,xb[s].x,xb[s].y,xb[s].z,xb[s].w};
    float qv[8];
    #pragma unroll
    for (int e = 0; e < 8; ++e) qv[e] = cv[e] * cv[e];
    split8(cv, ah[s], al[s]);
    split8(qv, ah[s + 4], al[s + 4]);
  }

  // ---- acc init: acc[ct] reg j -> cluster col*8+ct ----
  f32x16 acc[8];
  {
    float4 b0 = *(const float4*)(base + col * 8);
    float4 b1 = *(const float4*)(base + col * 8 + 4);
    float bb[8] = {b0.x,b0.y,b0.z,b0.w,b1.x,b1.y,b1.z,b1.w};
    #pragma unroll
    for (int ct = 0; ct < 8; ++ct) {
      #pragma unroll
      for (int j = 0; j < 16; ++j) acc[ct][j] = bb[ct];
    }
  }

  {
    f32x4* dst = (f32x4*)W_sh[0];
    #pragma unroll
    for (int i = 0; i < 4; ++i) dst[i * 256 + tid] = st[i];   // waits chunk0
    #pragma unroll
    for (int i = 0; i < 4; ++i) st[i] = Wv[1024 + i * 256 + tid];  // chunk1
  }
  __syncthreads();

  // ---- chunk loop: c<4 Wh slices 2c,2c+1 (ah+al); c>=4 Wl (ah only) ----
  #pragma unroll
  for (int c = 0; c < 8; ++c) {
    const _Float16* Ws = W_sh[c & 1];
    #pragma unroll
    for (int f = 0; f < 16; ++f) {
      const int ct = f & 7;
      f16x8 b = *(const f16x8*)&Ws[f * 512 + lane * 8];
      if (c < 4) {
        const int s = 2 * c + (f >> 3);
        acc[ct] = __builtin_amdgcn_mfma_f32_32x32x16_f16(ah[s], b, acc[ct], 0, 0, 0);
        acc[ct] = __builtin_amdgcn_mfma_f32_32x32x16_f16(al[s], b, acc[ct], 0, 0, 0);
      } else {
        const int s = 2 * (c - 4) + (f >> 3);
        acc[ct] = __builtin_amdgcn_mfma_f32_32x32x16_f16(ah[s], b, acc[ct], 0, 0, 0);
      }
    }
    if (c < 7) {
      f32x4* dst = (f32x4*)W_sh[(c + 1) & 1];
      #pragma unroll
      for (int i = 0; i < 4; ++i) dst[i * 256 + tid] = st[i];
      if (c < 6) {
        #pragma unroll
        for (int i = 0; i < 4; ++i)
          st[i] = Wv[(size_t)(c + 2) * 1024 + i * 256 + tid];
      }
      __syncthreads();
    }
  }

  // ---- softmax epilogue; reg j -> row (j&3)+8*(j>>2)+4*h, lane owns 8 cols ----
  float wls = 0.0f;
  #pragma unroll
  for (int j = 0; j < 16; ++j) {
    const int r = (j & 3) + 8 * (j >> 2) + 4 * h;
    float m = acc[0][j];
    #pragma unroll
    for (int ct = 1; ct < 8; ++ct) m = fmaxf(m, acc[ct][j]);
    m = fmaxf(m, __shfl_xor(m, 1, 64));
    m = fmaxf(m, __shfl_xor(m, 2, 64));
    m = fmaxf(m, __shfl_xor(m, 4, 64));
    m = fmaxf(m, __shfl_xor(m, 8, 64));
    m = fmaxf(m, __shfl_xor(m, 16, 64));
    float ev[8]; float s = 0.0f;
    #pragma unroll
    for (int ct = 0; ct < 8; ++ct) { ev[ct] = __expf(acc[ct][j] - m); s += ev[ct]; }
    s += __shfl_xor(s, 1, 64);
    s += __shfl_xor(s, 2, 64);
    s += __shfl_xor(s, 4, 64);
    s += __shfl_xor(s, 8, 64);
    s += __shfl_xor(s, 16, 64);
    float rs = 1.0f / s;
    float* pr = pi + (size_t)(row0 + r) * KCL + col * 8;
    f32x4 p0 = { ev[0]*rs, ev[1]*rs, ev[2]*rs, ev[3]*rs };
    f32x4 p1 = { ev[4]*rs, ev[5]*rs, ev[6]*rs, ev[7]*rs };
    *(f32x4*)(pr + 0) = p0;
    *(f32x4*)(pr + 4) = p1;
    wls += m + __logf(s);       // identical across the 32 lanes of this row
  }
  wls += __shfl_xor(wls, 1, 64);
  wls += __shfl_xor(wls, 2, 64);
  wls += __shfl_xor(wls, 4, 64);
  wls += __shfl_xor(wls, 8, 64);
  wls += __shfl_xor(wls, 16, 64);
  wls += __shfl_xor(wls, 32, 64);
  if (lane == 0) partial[blockIdx.x * WAVES_PER_BLK + w] = wls * 0.03125f; // /32
}

__global__ void dpmm_fin(const float* __restrict__ ws,
                         float* __restrict__ out_elbo) {
  __shared__ double red[256];
  const int t = threadIdx.x;
  double s = 0.0;
  for (int i = t; i < NPART; i += 256) s += (double)ws[OFF_PART + i];
  s -= (double)ws[OFF_KLP + t];
  red[t] = s;
  __syncthreads();
  for (int off = 128; off; off >>= 1) {
    if (t < off) red[t] += red[t + off];
    __syncthreads();
  }
  if (t == 0) out_elbo[0] = (float)(red[0] - (double)ws[OFF_KLB]);
}

extern "C" void kernel_launch(void* const* d_in, const int* in_sizes, int n_in,
                              void* d_out, int out_size, void* d_ws, size_t ws_size,
                              hipStream_t stream) {
  const float* x    = (const float*)d_in[0];
  const float* u    = (const float*)d_in[1];
  const float* v    = (const float*)d_in[2];
  const float* tau  = (const float*)d_in[3];
  const float* c    = (const float*)d_in[4];
  const float* n    = (const float*)d_in[5];
  const float* B    = (const float*)d_in[6];
  const float* tau0 = (const float*)d_in[7];
  const float* c0   = (const float*)d_in[8];
  const float* n0   = (const float*)d_in[9];
  const float* B0   = (const float*)d_in[10];

  float* out = (float*)d_out;
  float* ws  = (float*)d_ws;

  dpmm_beta<<<1, KCL, 0, stream>>>(u, v, ws);
  dpmm_w<<<KCL, DDIM, 0, stream>>>(tau, c, n, B, tau0, c0, n0, B0, ws);

  const _Float16* Wp = (const _Float16*)ws;
  const float* base  = ws + OFF_BASE;
  float* partial     = ws + OFF_PART;

  dpmm_mfma<<<NBLK_MAIN, 256, 0, stream>>>(x, Wp, base, out, partial);
  dpmm_fin<<<1, 256, 0, stream>>>(ws, out + (size_t)NPTS * KCL);
}

// Round 14
// 117.522 us; speedup vs baseline: 6.7047x; 1.0252x over previous
//
#include <hip/hip_runtime.h>
#include <math.h>
#include <stdint.h>

#define NPTS 262144
#define KCL  256
#define DDIM 64
#define ALPHA_DP 1.0f

#define ROWS_PER_WAVE 32
#define WAVES_PER_BLK 4
#define ROWS_PER_BLK  (ROWS_PER_WAVE * WAVES_PER_BLK)   // 128
#define NBLK_MAIN     (NPTS / ROWS_PER_BLK)             // 2048
#define NPART         (NPTS / ROWS_PER_WAVE)            // 8192

// ws float offsets
#define OFF_ELOGPI 32768
#define OFF_BASE   33024
#define OFF_KLB    33280
#define OFF_KLP    33281
#define OFF_PART   33537

#define LN2_F    0.6931471805599453f
#define LOG2PI_F 1.8378770664093453f

typedef _Float16 f16x8  __attribute__((ext_vector_type(8)));
typedef float    f32x4  __attribute__((ext_vector_type(4)));
typedef float    f32x16 __attribute__((ext_vector_type(16)));

__device__ __forceinline__ float digamma_f(float x) {
  float r = 0.0f;
  while (x < 6.0f) { r -= 1.0f / x; x += 1.0f; }
  float inv  = 1.0f / x;
  float inv2 = inv * inv;
  return r + logf(x) - 0.5f * inv
       - inv2 * (0.083333333333333333f
         - inv2 * (0.008333333333333333f
           - inv2 * 0.003968253968253968f));
}

// --- P1: stick-breaking terms + cumsum + KL(Beta) --------------------------
__global__ void dpmm_beta(const float* __restrict__ u, const float* __restrict__ v,
                          float* __restrict__ ws) {
  __shared__ float eb_s[KCL], e1b_s[KCL], klb_s[KCL];
  const int k = threadIdx.x;
  float uk = u[k], vk = v[k];
  float ds  = digamma_f(uk + vk);
  float eb  = digamma_f(uk) - ds;
  float e1b = digamma_f(vk) - ds;
  eb_s[k] = eb; e1b_s[k] = e1b;
  klb_s[k] = lgammaf(uk + vk) - lgammaf(uk) - lgammaf(vk)
           - (lgammaf(1.0f + ALPHA_DP) - lgammaf(ALPHA_DP))
           + (uk - 1.0f) * eb + (vk - ALPHA_DP) * e1b;
  __syncthreads();
  if (k == 0) {
    float run = 0.0f;
    for (int j = 0; j < KCL; ++j) { ws[OFF_ELOGPI + j] = eb_s[j] + run; run += e1b_s[j]; }
    double t = 0.0;
    for (int j = 0; j < KCL; ++j) t += (double)klb_s[j];
    ws[OFF_KLB] = (float)t;
  }
}

// --- P2: W split into 32x32x16 B-fragments + per-k base & KL parts ---------
// Frag layout: frag fi (0..63 Wh, 64..127 Wl), fi%64 = s*8 + ct, s=krow>>4.
//   element: Wp[fi*512 + lane*8 + e];  b-frag: col=lane&31, k=(lane>>5)*8+e
// Cluster k at tile ct=k&7, col=k>>3  -> lane owns 8 contiguous clusters.
__global__ __launch_bounds__(64) void dpmm_w(
    const float* __restrict__ tau, const float* __restrict__ c,
    const float* __restrict__ n,   const float* __restrict__ B,
    const float* __restrict__ tau0, const float* __restrict__ c0,
    const float* __restrict__ n0,  const float* __restrict__ B0,
    float* __restrict__ ws) {
  const int k = blockIdx.x, d = threadIdx.x;
  _Float16* Wp = (_Float16*)ws;

  float nk = n[k], ck = c[k], n0k = n0[k], c0k = c0[k];
  float Bkd = B[k * DDIM + d],   tkd  = tau[k * DDIM + d];
  float B0kd = B0[k * DDIM + d], t0kd = tau0[k * DDIM + d];
  float Elam = nk / Bkd;
  float wb = Elam * tkd;        // coeff of x   (krow d)
  float wa = -0.5f * Elam;      // coeff of x^2 (krow 64+d)

  const int ct = k & 7, col = k >> 3;
  int   kks[2] = { d, 64 + d };
  float wvs[2] = { wb, wa };
  #pragma unroll
  for (int q = 0; q < 2; ++q) {
    int kk = kks[q]; float wq = wvs[q];
    int s = kk >> 4, rem = kk & 15, h = rem >> 3, e = rem & 7;
    int lanei = col + h * 32;
    _Float16 hi = (_Float16)wq, lo = (_Float16)(wq - (float)hi);
    Wp[(( s * 8 + ct)      ) * 512 + lanei * 8 + e] = hi;
    Wp[((64 + s * 8 + ct)  ) * 512 + lanei * 8 + e] = lo;
  }

  float a = 0.5f * nk, a0 = 0.5f * n0k;
  float dga = digamma_f(a);
  float lga = lgammaf(a), lga0 = lgammaf(a0);
  float b = 0.5f * Bkd, b0 = 0.5f * B0kd;
  float klg = (a - a0) * dga - lga + lga0
            + a0 * (logf(b) - logf(b0)) + a * (b0 - b) / b;
  float dt = tkd - t0kd;
  float knq = Elam * dt * dt;
  float negLogB = -logf(Bkd);
  float et2 = Elam * tkd * tkd;

  #pragma unroll
  for (int off = 32; off; off >>= 1) {
    klg      += __shfl_xor(klg, off, 64);
    knq      += __shfl_xor(knq, off, 64);
    negLogB  += __shfl_xor(negLogB, off, 64);
    et2      += __shfl_xor(et2, off, 64);
  }
  if (d == 0) {
    float sumEloglam = (float)DDIM * (dga + LN2_F) + negLogB;
    ws[OFF_BASE + k] = ws[OFF_ELOGPI + k]
        + 0.5f * (sumEloglam - (float)DDIM * LOG2PI_F
                  - (float)DDIM / ck - et2);
    float kln = 0.5f * (float)DDIM * (c0k / ck - 1.0f + logf(ck / c0k))
              + 0.5f * c0k * knq;
    ws[OFF_KLP + k] = klg + kln;
  }
}

__device__ __forceinline__ void split8(const float* v, f16x8& h, f16x8& l) {
  #pragma unroll
  for (int e = 0; e < 8; ++e) {
    _Float16 hh = (_Float16)v[e];
    h[e] = hh;
    l[e] = (_Float16)(v[e] - (float)hh);
  }
}

// direct global->LDS DMA, 16B per lane; LDS dest = wave-uniform base + lane*16
__device__ __forceinline__ void gload16(const _Float16* g, _Float16* l) {
  __builtin_amdgcn_global_load_lds(
      reinterpret_cast<const __attribute__((address_space(1))) uint32_t*>(
          reinterpret_cast<uintptr_t>(g)),
      reinterpret_cast<__attribute__((address_space(3))) uint32_t*>(
          reinterpret_cast<uintptr_t>(l)),
      16, 0, 0);
}

// 32x32x16 MFMA, 32 rows/wave; W staged via global_load_lds in 4x 32KB
// chunks, double-buffered (64 KB LDS -> 2 blocks/CU). 4 barriers/block;
// chunk c+1 DMA is in flight across all of chunk c's GEMM.
__global__ __launch_bounds__(256, 2) void dpmm_mfma(
    const float* __restrict__ x, const _Float16* __restrict__ Wp,
    const float* __restrict__ base,
    float* __restrict__ pi, float* __restrict__ partial) {
  __shared__ _Float16 W_sh[2][16384];           // 2 x 32KB chunk buffers
  const int tid  = threadIdx.x;
  const int lane = tid & 63;
  const int w    = tid >> 6;
  const int col  = lane & 31;                   // tile col / A row
  const int h    = lane >> 5;                   // k-half

  // ---- x loads first (in flight during chunk0 DMA) ----
  const long row0 = (long)blockIdx.x * ROWS_PER_BLK + (long)w * ROWS_PER_WAVE;
  const float* xr = x + (row0 + col) * DDIM + h * 8;
  float4 xa[4], xb[4];
  #pragma unroll
  for (int s = 0; s < 4; ++s) {
    xa[s] = *(const float4*)(xr + s * 16);
    xb[s] = *(const float4*)(xr + s * 16 + 4);
  }

  // ---- issue chunk0 DMA ----
  #pragma unroll
  for (int i = 0; i < 8; ++i)
    gload16(Wp + (i * 256 + tid) * 8, &W_sh[0][(i * 256 + w * 64) * 8]);

  // ---- A fragments: s=0..3 x, s=4..7 x^2 (hi/lo) ----
  f16x8 ah[8], al[8];
  #pragma unroll
  for (int s = 0; s < 4; ++s) {
    float cv[8] = {xa[s].x,xa[s].y,xa[s].z,xa[s].w,xb[s].x,xb[s].y,xb[s].z,xb[s].w};
    float qv[8];
    #pragma unroll
    for (int e = 0; e < 8; ++e) qv[e] = cv[e] * cv[e];
    split8(cv, ah[s], al[s]);
    split8(qv, ah[s + 4], al[s + 4]);
  }

  // ---- acc init: acc[ct] reg j -> cluster col*8+ct ----
  f32x16 acc[8];
  {
    float4 b0 = *(const float4*)(base + col * 8);
    float4 b1 = *(const float4*)(base + col * 8 + 4);
    float bb[8] = {b0.x,b0.y,b0.z,b0.w,b1.x,b1.y,b1.z,b1.w};
    #pragma unroll
    for (int ct = 0; ct < 8; ++ct) {
      #pragma unroll
      for (int j = 0; j < 16; ++j) acc[ct][j] = bb[ct];
    }
  }

  __syncthreads();                              // chunk0 landed

  // ---- chunk loop: chunk c GEMM || chunk c+1 DMA ----
  // chunk 0: Wh s=0..3 (ah+al) | 1: Wh s=4..7 (ah+al) | 2: Wl s=0..3 (ah) |
  // 3: Wl s=4..7 (ah)
  #pragma unroll
  for (int c = 0; c < 4; ++c) {
    if (c + 1 < 4) {
      #pragma unroll
      for (int i = 0; i < 8; ++i)
        gload16(Wp + (size_t)(c + 1) * 16384 + (i * 256 + tid) * 8,
                &W_sh[(c + 1) & 1][(i * 256 + w * 64) * 8]);
    }
    const _Float16* Ws = W_sh[c & 1];
    #pragma unroll
    for (int f = 0; f < 32; ++f) {
      const int ss = f >> 3, ct = f & 7;
      f16x8 b = *(const f16x8*)&Ws[f * 512 + lane * 8];
      if (c == 0) {
        acc[ct] = __builtin_amdgcn_mfma_f32_32x32x16_f16(ah[ss], b, acc[ct], 0, 0, 0);
        acc[ct] = __builtin_amdgcn_mfma_f32_32x32x16_f16(al[ss], b, acc[ct], 0, 0, 0);
      } else if (c == 1) {
        acc[ct] = __builtin_amdgcn_mfma_f32_32x32x16_f16(ah[4 + ss], b, acc[ct], 0, 0, 0);
        acc[ct] = __builtin_amdgcn_mfma_f32_32x32x16_f16(al[4 + ss], b, acc[ct], 0, 0, 0);
      } else if (c == 2) {
        acc[ct] = __builtin_amdgcn_mfma_f32_32x32x16_f16(ah[ss], b, acc[ct], 0, 0, 0);
      } else {
        acc[ct] = __builtin_amdgcn_mfma_f32_32x32x16_f16(ah[4 + ss], b, acc[ct], 0, 0, 0);
      }
    }
    if (c + 1 < 4) __syncthreads();             // drains chunk c+1 DMA
  }

  // ---- softmax epilogue; reg j -> row (j&3)+8*(j>>2)+4*h, lane owns 8 cols ----
  float wls = 0.0f;
  #pragma unroll
  for (int j = 0; j < 16; ++j) {
    const int r = (j & 3) + 8 * (j >> 2) + 4 * h;
    float m = acc[0][j];
    #pragma unroll
    for (int ct = 1; ct < 8; ++ct) m = fmaxf(m, acc[ct][j]);
    m = fmaxf(m, __shfl_xor(m, 1, 64));
    m = fmaxf(m, __shfl_xor(m, 2, 64));
    m = fmaxf(m, __shfl_xor(m, 4, 64));
    m = fmaxf(m, __shfl_xor(m, 8, 64));
    m = fmaxf(m, __shfl_xor(m, 16, 64));
    float ev[8]; float s = 0.0f;
    #pragma unroll
    for (int ct = 0; ct < 8; ++ct) { ev[ct] = __expf(acc[ct][j] - m); s += ev[ct]; }
    s += __shfl_xor(s, 1, 64);
    s += __shfl_xor(s, 2, 64);
    s += __shfl_xor(s, 4, 64);
    s += __shfl_xor(s, 8, 64);
    s += __shfl_xor(s, 16, 64);
    float rs = 1.0f / s;
    float* pr = pi + (size_t)(row0 + r) * KCL + col * 8;
    f32x4 p0 = { ev[0]*rs, ev[1]*rs, ev[2]*rs, ev[3]*rs };
    f32x4 p1 = { ev[4]*rs, ev[5]*rs, ev[6]*rs, ev[7]*rs };
    *(f32x4*)(pr + 0) = p0;
    *(f32x4*)(pr + 4) = p1;
    wls += m + __logf(s);       // identical across the 32 lanes of this row
  }
  wls += __shfl_xor(wls, 1, 64);
  wls += __shfl_xor(wls, 2, 64);
  wls += __shfl_xor(wls, 4, 64);
  wls += __shfl_xor(wls, 8, 64);
  wls += __shfl_xor(wls, 16, 64);
  wls += __shfl_xor(wls, 32, 64);
  if (lane == 0) partial[blockIdx.x * WAVES_PER_BLK + w] = wls * 0.03125f; // /32
}

__global__ void dpmm_fin(const float* __restrict__ ws,
                         float* __restrict__ out_elbo) {
  __shared__ double red[256];
  const int t = threadIdx.x;
  double s = 0.0;
  for (int i = t; i < NPART; i += 256) s += (double)ws[OFF_PART + i];
  s -= (double)ws[OFF_KLP + t];
  red[t] = s;
  __syncthreads();
  for (int off = 128; off; off >>= 1) {
    if (t < off) red[t] += red[t + off];
    __syncthreads();
  }
  if (t == 0) out_elbo[0] = (float)(red[0] - (double)ws[OFF_KLB]);
}

extern "C" void kernel_launch(void* const* d_in, const int* in_sizes, int n_in,
                              void* d_out, int out_size, void* d_ws, size_t ws_size,
                              hipStream_t stream) {
  const float* x    = (const float*)d_in[0];
  const float* u    = (const float*)d_in[1];
  const float* v    = (const float*)d_in[2];
  const float* tau  = (const float*)d_in[3];
  const float* c    = (const float*)d_in[4];
  const float* n    = (const float*)d_in[5];
  const float* B    = (const float*)d_in[6];
  const float* tau0 = (const float*)d_in[7];
  const float* c0   = (const float*)d_in[8];
  const float* n0   = (const float*)d_in[9];
  const float* B0   = (const float*)d_in[10];

  float* out = (float*)d_out;
  float* ws  = (float*)d_ws;

  dpmm_beta<<<1, KCL, 0, stream>>>(u, v, ws);
  dpmm_w<<<KCL, DDIM, 0, stream>>>(tau, c, n, B, tau0, c0, n0, B0, ws);

  const _Float16* Wp = (const _Float16*)ws;
  const float* base  = ws + OFF_BASE;
  float* partial     = ws + OFF_PART;

  dpmm_mfma<<<NBLK_MAIN, 256, 0, stream>>>(x, Wp, base, out, partial);
  dpmm_fin<<<1, 256, 0, stream>>>(ws, out + (size_t)NPTS * KCL);
}